// Round 1
// baseline (640.003 us; speedup 1.0000x reference)
//
#include <hip/hip_runtime.h>
#include <math.h>

#define D 64

// ---------------- CSR build ----------------

__global__ void hist_kernel(const int* __restrict__ dst, int* __restrict__ deg, int e) {
    int i = blockIdx.x * blockDim.x + threadIdx.x;
    if (i < e) atomicAdd(&deg[dst[i]], 1);
}

__global__ void scan1_kernel(const int* __restrict__ deg, int* __restrict__ rs,
                             int* __restrict__ bsum, int n) {
    __shared__ int s[1024];
    int t = threadIdx.x;
    int i = blockIdx.x * 1024 + t;
    int v = (i < n) ? deg[i] : 0;
    s[t] = v;
    __syncthreads();
    for (int off = 1; off < 1024; off <<= 1) {
        int add = (t >= off) ? s[t - off] : 0;
        __syncthreads();
        s[t] += add;
        __syncthreads();
    }
    if (i < n) rs[i] = s[t] - v;                 // exclusive within block
    if (t == 1023) bsum[blockIdx.x] = s[1023];   // block total
}

__global__ void scan2_kernel(int* __restrict__ bsum, int nb) {
    __shared__ int s[128];
    int t = threadIdx.x;
    int v = (t < nb) ? bsum[t] : 0;
    s[t] = v;
    __syncthreads();
    for (int off = 1; off < 128; off <<= 1) {
        int add = (t >= off) ? s[t - off] : 0;
        __syncthreads();
        s[t] += add;
        __syncthreads();
    }
    if (t < nb) bsum[t] = s[t] - v;              // exclusive block offsets
}

__global__ void scan3_kernel(int* __restrict__ rs, int* __restrict__ cursor,
                             const int* __restrict__ bsum, int n) {
    int i = blockIdx.x * 1024 + threadIdx.x;
    if (i < n) {
        int r = rs[i] + bsum[blockIdx.x];
        rs[i] = r;
        cursor[i] = r;
    }
}

__global__ void scatter_kernel(const int* __restrict__ src, const int* __restrict__ dst,
                               int* __restrict__ cursor, int* __restrict__ csr, int e) {
    int i = blockIdx.x * blockDim.x + threadIdx.x;
    if (i < e) {
        int p = atomicAdd(&cursor[dst[i]], 1);
        csr[p] = src[i];
    }
}

// ---------------- SAGE layer: aggregate + normalize + GEMM (+ReLU) ----------------
// One 64-lane wave per node; lane = feature dim. W staged in LDS.

template<int RELU>
__global__ __launch_bounds__(512) void sage_layer_kernel(
    const float* __restrict__ in, float* __restrict__ out,
    const float* __restrict__ W, const float* __restrict__ bias,
    const int* __restrict__ rs, const int* __restrict__ deg,
    const int* __restrict__ csr, int n)
{
    __shared__ float Wl[D * D];
    __shared__ float bl[D];
    for (int i = threadIdx.x; i < D * D; i += blockDim.x) Wl[i] = W[i];
    if (threadIdx.x < D) bl[threadIdx.x] = bias[threadIdx.x];
    __syncthreads();

    const int lane = threadIdx.x & 63;
    const int wid  = threadIdx.x >> 6;
    const int v    = blockIdx.x * (blockDim.x >> 6) + wid;
    if (v >= n) return;

    const int beg = rs[v];
    const int cnt = deg[v];
    const int end = beg + cnt;

    float a = in[(size_t)v * D + lane];          // self term
    int e = beg;
    for (; e + 4 <= end; e += 4) {               // unroll 4: keep 4 row-gathers in flight
        int s0 = csr[e], s1 = csr[e + 1], s2 = csr[e + 2], s3 = csr[e + 3];
        a += in[(size_t)s0 * D + lane];
        a += in[(size_t)s1 * D + lane];
        a += in[(size_t)s2 * D + lane];
        a += in[(size_t)s3 * D + lane];
    }
    for (; e < end; ++e) a += in[(size_t)csr[e] * D + lane];

    a *= 1.0f / (float)(cnt + 1);

    // row-vector @ W: lane j computes out[j] = sum_k a[k] * W[k][j]
    float o = bl[lane];
    #pragma unroll
    for (int k = 0; k < D; ++k) {
        o = fmaf(__shfl(a, k), Wl[k * D + lane], o);
    }
    if (RELU) o = fmaxf(o, 0.0f);
    out[(size_t)v * D + lane] = o;
}

// ---------------- Scoring: dot + softplus, reduced to a double accumulator ----------------
// 16 lanes per pair, float4 loads (256B coalesced per row).

__global__ __launch_bounds__(256) void score_kernel(
    const float* __restrict__ emb,
    const int* __restrict__ a_idx, const int* __restrict__ b_idx,
    int npairs, float sign, double* __restrict__ accum)
{
    const int ll  = threadIdx.x & 15;
    const int gib = threadIdx.x >> 4;                 // group in block: 0..15
    const int gpb = blockDim.x >> 4;
    int g = blockIdx.x * gpb + gib;
    const int ngroups = gridDim.x * gpb;

    float local = 0.0f;
    for (int p = g; p < npairs; p += ngroups) {
        int ai = a_idx[p];
        int bi = b_idx[p];
        const float4 va = *(const float4*)(emb + (size_t)ai * D + ll * 4);
        const float4 vb = *(const float4*)(emb + (size_t)bi * D + ll * 4);
        float d = va.x * vb.x + va.y * vb.y + va.z * vb.z + va.w * vb.w;
        d += __shfl_xor(d, 1);
        d += __shfl_xor(d, 2);
        d += __shfl_xor(d, 4);
        d += __shfl_xor(d, 8);
        if (ll == 0) {
            float x = sign * d;
            // stable softplus(x) = max(x,0) + log1p(exp(-|x|)) ; term = -log_sigmoid(-x)
            local += fmaxf(x, 0.0f) + log1pf(expf(-fabsf(x)));
        }
    }

    __shared__ float red[256];
    red[threadIdx.x] = local;
    __syncthreads();
    for (int s = blockDim.x / 2; s > 0; s >>= 1) {
        if ((int)threadIdx.x < s) red[threadIdx.x] += red[threadIdx.x + s];
        __syncthreads();
    }
    if (threadIdx.x == 0) atomicAdd(accum, (double)red[0]);
}

__global__ void finalize_kernel(const double* __restrict__ acc, float* __restrict__ out, int ep) {
    if (threadIdx.x == 0 && blockIdx.x == 0)
        out[0] = (float)(acc[0] / (double)ep);
}

// ---------------- launch ----------------

extern "C" void kernel_launch(void* const* d_in, const int* in_sizes, int n_in,
                              void* d_out, int out_size, void* d_ws, size_t ws_size,
                              hipStream_t stream) {
    const float* features = (const float*)d_in[0];
    const float* W1 = (const float*)d_in[1];
    const float* b1 = (const float*)d_in[2];
    const float* W2 = (const float*)d_in[3];
    const float* b2 = (const float*)d_in[4];
    const int* src     = (const int*)d_in[5];
    const int* dst     = (const int*)d_in[6];
    const int* pos_src = (const int*)d_in[7];
    const int* pos_dst = (const int*)d_in[8];
    const int* neg_src = (const int*)d_in[9];
    const int* neg_dst = (const int*)d_in[10];

    const int N    = in_sizes[0] / D;
    const int E    = in_sizes[5];
    const int EP   = in_sizes[7];
    const int ENEG = in_sizes[9];

    char* ws = (char*)d_ws;
    size_t off = 0;
    auto alloc = [&](size_t bytes) -> void* {
        void* p = ws + off;
        off += (bytes + 255) & ~(size_t)255;
        return p;
    };
    int*    deg    = (int*)   alloc((size_t)N * 4);
    int*    rs     = (int*)   alloc((size_t)(N + 1) * 4);
    int*    cursor = (int*)   alloc((size_t)N * 4);
    int*    bsum   = (int*)   alloc(1024 * 4);
    int*    csr    = (int*)   alloc((size_t)E * 4);
    float*  h      = (float*) alloc((size_t)N * D * 4);
    float*  emb    = (float*) alloc((size_t)N * D * 4);
    double* acc    = (double*)alloc(8);

    hipMemsetAsync(deg, 0, (size_t)N * 4, stream);
    hipMemsetAsync(acc, 0, 8, stream);

    const int eb  = (E + 255) / 256;
    const int nb1 = (N + 1023) / 1024;   // 98 for N=100000, fits scan2's 128 threads

    hist_kernel<<<eb, 256, 0, stream>>>(dst, deg, E);
    scan1_kernel<<<nb1, 1024, 0, stream>>>(deg, rs, bsum, N);
    scan2_kernel<<<1, 128, 0, stream>>>(bsum, nb1);
    scan3_kernel<<<nb1, 1024, 0, stream>>>(rs, cursor, bsum, N);
    scatter_kernel<<<eb, 256, 0, stream>>>(src, dst, cursor, csr, E);

    const int lb = (N + 7) / 8;          // 8 waves (nodes) per 512-thread block
    sage_layer_kernel<1><<<lb, 512, 0, stream>>>(features, h, W1, b1, rs, deg, csr, N);
    sage_layer_kernel<0><<<lb, 512, 0, stream>>>(h, emb, W2, b2, rs, deg, csr, N);

    int pb = (EP + 15) / 16;  if (pb > 2048) pb = 2048;
    score_kernel<<<pb, 256, 0, stream>>>(emb, pos_src, pos_dst, EP, -1.0f, acc);
    int ngb = (ENEG + 15) / 16; if (ngb > 4096) ngb = 4096;
    score_kernel<<<ngb, 256, 0, stream>>>(emb, neg_src, neg_dst, ENEG, 1.0f, acc);

    finalize_kernel<<<1, 64, 0, stream>>>(acc, (float*)d_out, EP);
}

// Round 2
// 613.432 us; speedup vs baseline: 1.0433x; 1.0433x over previous
//
#include <hip/hip_runtime.h>
#include <hip/hip_fp16.h>
#include <math.h>

#define D 64

// ---------------- CSR build ----------------

__global__ void hist_kernel(const int* __restrict__ dst, int* __restrict__ deg, int e) {
    int i = blockIdx.x * blockDim.x + threadIdx.x;
    if (i < e) atomicAdd(&deg[dst[i]], 1);
}

__global__ void scan1_kernel(const int* __restrict__ deg, int* __restrict__ rs,
                             int* __restrict__ bsum, int n) {
    __shared__ int s[1024];
    int t = threadIdx.x;
    int i = blockIdx.x * 1024 + t;
    int v = (i < n) ? deg[i] : 0;
    s[t] = v;
    __syncthreads();
    for (int off = 1; off < 1024; off <<= 1) {
        int add = (t >= off) ? s[t - off] : 0;
        __syncthreads();
        s[t] += add;
        __syncthreads();
    }
    if (i < n) rs[i] = s[t] - v;                 // exclusive within block
    if (t == 1023) bsum[blockIdx.x] = s[1023];   // block total
}

__global__ void scan2_kernel(int* __restrict__ bsum, int nb) {
    __shared__ int s[128];
    int t = threadIdx.x;
    int v = (t < nb) ? bsum[t] : 0;
    s[t] = v;
    __syncthreads();
    for (int off = 1; off < 128; off <<= 1) {
        int add = (t >= off) ? s[t - off] : 0;
        __syncthreads();
        s[t] += add;
        __syncthreads();
    }
    if (t < nb) bsum[t] = s[t] - v;              // exclusive block offsets
}

__global__ void scan3_kernel(int* __restrict__ rs, int* __restrict__ cursor,
                             const int* __restrict__ bsum, int n) {
    int i = blockIdx.x * 1024 + threadIdx.x;
    if (i < n) {
        int r = rs[i] + bsum[blockIdx.x];
        rs[i] = r;
        cursor[i] = r;
    }
}

__global__ void scatter_kernel(const int* __restrict__ src, const int* __restrict__ dst,
                               int* __restrict__ cursor, int* __restrict__ csr, int e) {
    int i = blockIdx.x * blockDim.x + threadIdx.x;
    if (i < e) {
        int p = atomicAdd(&cursor[dst[i]], 1);
        csr[p] = src[i];
    }
}

// ---------------- fp32 -> fp16 conversion (features table) ----------------

__global__ __launch_bounds__(256) void f2h_kernel(const float* __restrict__ in,
                                                  __half* __restrict__ out, int n4) {
    int i = blockIdx.x * blockDim.x + threadIdx.x;
    if (i < n4) {
        float4 v = *(const float4*)(in + (size_t)i * 4);
        union { __half2 h[2]; float2 f; } u;
        u.h[0] = __floats2half2_rn(v.x, v.y);
        u.h[1] = __floats2half2_rn(v.z, v.w);
        *(float2*)(out + (size_t)i * 4) = u.f;
    }
}

// ---------------- SAGE layer: aggregate + normalize + GEMM (+ReLU) ----------------
// One 64-lane wave per node; lane = feature dim. fp16 storage, fp32 math.
// W staged in LDS (fp32).

template<int RELU>
__global__ __launch_bounds__(512) void sage_layer_kernel(
    const __half* __restrict__ in, __half* __restrict__ out,
    const float* __restrict__ W, const float* __restrict__ bias,
    const int* __restrict__ rs, const int* __restrict__ deg,
    const int* __restrict__ csr, int n)
{
    __shared__ float Wl[D * D];
    __shared__ float bl[D];
    for (int i = threadIdx.x; i < D * D; i += blockDim.x) Wl[i] = W[i];
    if (threadIdx.x < D) bl[threadIdx.x] = bias[threadIdx.x];
    __syncthreads();

    const int lane = threadIdx.x & 63;
    const int wid  = threadIdx.x >> 6;
    const int v    = blockIdx.x * (blockDim.x >> 6) + wid;
    if (v >= n) return;

    const int beg = rs[v];
    const int cnt = deg[v];
    const int end = beg + cnt;

    float a = __half2float(in[(size_t)v * D + lane]);    // self term
    int e = beg;
    for (; e + 4 <= end; e += 4) {                       // unroll 4: 4 gathers in flight
        int s0 = csr[e], s1 = csr[e + 1], s2 = csr[e + 2], s3 = csr[e + 3];
        float f0 = __half2float(in[(size_t)s0 * D + lane]);
        float f1 = __half2float(in[(size_t)s1 * D + lane]);
        float f2 = __half2float(in[(size_t)s2 * D + lane]);
        float f3 = __half2float(in[(size_t)s3 * D + lane]);
        a += (f0 + f1) + (f2 + f3);
    }
    for (; e < end; ++e) a += __half2float(in[(size_t)csr[e] * D + lane]);

    a *= 1.0f / (float)(cnt + 1);

    // row-vector @ W: lane j computes out[j] = sum_k a[k] * W[k][j]
    float o = bl[lane];
    #pragma unroll
    for (int k = 0; k < D; ++k) {
        o = fmaf(__shfl(a, k), Wl[k * D + lane], o);
    }
    if (RELU) o = fmaxf(o, 0.0f);
    out[(size_t)v * D + lane] = __float2half(o);
}

// ---------------- Scoring: dot + softplus, reduced to a double accumulator ----------------
// 16 lanes per pair; each lane loads 8 B (4 halves) per row -> 128 B coalesced per row.

__global__ __launch_bounds__(256) void score_kernel(
    const __half* __restrict__ emb,
    const int* __restrict__ a_idx, const int* __restrict__ b_idx,
    int npairs, float sign, double* __restrict__ accum)
{
    const int ll  = threadIdx.x & 15;
    const int gib = threadIdx.x >> 4;                 // group in block: 0..15
    const int gpb = blockDim.x >> 4;
    int g = blockIdx.x * gpb + gib;
    const int ngroups = gridDim.x * gpb;

    float local = 0.0f;
    for (int p = g; p < npairs; p += ngroups) {
        int ai = a_idx[p];
        int bi = b_idx[p];
        float2 fa = *(const float2*)(emb + (size_t)ai * D + ll * 4);
        float2 fb = *(const float2*)(emb + (size_t)bi * D + ll * 4);
        __half2 a0 = *reinterpret_cast<__half2*>(&fa.x);
        __half2 a1 = *reinterpret_cast<__half2*>(&fa.y);
        __half2 b0 = *reinterpret_cast<__half2*>(&fb.x);
        __half2 b1 = *reinterpret_cast<__half2*>(&fb.y);
        float2 A0 = __half22float2(a0), A1 = __half22float2(a1);
        float2 B0 = __half22float2(b0), B1 = __half22float2(b1);
        float d = A0.x * B0.x + A0.y * B0.y + A1.x * B1.x + A1.y * B1.y;
        d += __shfl_xor(d, 1);
        d += __shfl_xor(d, 2);
        d += __shfl_xor(d, 4);
        d += __shfl_xor(d, 8);
        if (ll == 0) {
            float x = sign * d;
            // stable softplus(x) = max(x,0) + log1p(exp(-|x|)) ; term = -log_sigmoid(-x)
            local += fmaxf(x, 0.0f) + log1pf(expf(-fabsf(x)));
        }
    }

    __shared__ float red[256];
    red[threadIdx.x] = local;
    __syncthreads();
    for (int s = blockDim.x / 2; s > 0; s >>= 1) {
        if ((int)threadIdx.x < s) red[threadIdx.x] += red[threadIdx.x + s];
        __syncthreads();
    }
    if (threadIdx.x == 0) atomicAdd(accum, (double)red[0]);
}

__global__ void finalize_kernel(const double* __restrict__ acc, float* __restrict__ out, int ep) {
    if (threadIdx.x == 0 && blockIdx.x == 0)
        out[0] = (float)(acc[0] / (double)ep);
}

// ---------------- launch ----------------

extern "C" void kernel_launch(void* const* d_in, const int* in_sizes, int n_in,
                              void* d_out, int out_size, void* d_ws, size_t ws_size,
                              hipStream_t stream) {
    const float* features = (const float*)d_in[0];
    const float* W1 = (const float*)d_in[1];
    const float* b1 = (const float*)d_in[2];
    const float* W2 = (const float*)d_in[3];
    const float* b2 = (const float*)d_in[4];
    const int* src     = (const int*)d_in[5];
    const int* dst     = (const int*)d_in[6];
    const int* pos_src = (const int*)d_in[7];
    const int* pos_dst = (const int*)d_in[8];
    const int* neg_src = (const int*)d_in[9];
    const int* neg_dst = (const int*)d_in[10];

    const int N    = in_sizes[0] / D;
    const int E    = in_sizes[5];
    const int EP   = in_sizes[7];
    const int ENEG = in_sizes[9];

    char* ws = (char*)d_ws;
    size_t off = 0;
    auto alloc = [&](size_t bytes) -> void* {
        void* p = ws + off;
        off += (bytes + 255) & ~(size_t)255;
        return p;
    };
    int*    deg    = (int*)   alloc((size_t)N * 4);
    int*    rs     = (int*)   alloc((size_t)(N + 1) * 4);
    int*    cursor = (int*)   alloc((size_t)N * 4);
    int*    bsum   = (int*)   alloc(1024 * 4);
    int*    csr    = (int*)   alloc((size_t)E * 4);
    __half* featH  = (__half*)alloc((size_t)N * D * 2);
    __half* hH     = (__half*)alloc((size_t)N * D * 2);
    __half* embH   = (__half*)alloc((size_t)N * D * 2);
    double* acc    = (double*)alloc(8);

    hipMemsetAsync(deg, 0, (size_t)N * 4, stream);
    hipMemsetAsync(acc, 0, 8, stream);

    const int eb  = (E + 255) / 256;
    const int nb1 = (N + 1023) / 1024;   // 98 for N=100000, fits scan2's 128 threads

    hist_kernel<<<eb, 256, 0, stream>>>(dst, deg, E);
    scan1_kernel<<<nb1, 1024, 0, stream>>>(deg, rs, bsum, N);
    scan2_kernel<<<1, 128, 0, stream>>>(bsum, nb1);
    scan3_kernel<<<nb1, 1024, 0, stream>>>(rs, cursor, bsum, N);
    scatter_kernel<<<eb, 256, 0, stream>>>(src, dst, cursor, csr, E);

    const int n4 = (N * D) / 4;
    f2h_kernel<<<(n4 + 255) / 256, 256, 0, stream>>>(features, featH, n4);

    const int lb = (N + 7) / 8;          // 8 waves (nodes) per 512-thread block
    sage_layer_kernel<1><<<lb, 512, 0, stream>>>(featH, hH, W1, b1, rs, deg, csr, N);
    sage_layer_kernel<0><<<lb, 512, 0, stream>>>(hH, embH, W2, b2, rs, deg, csr, N);

    int pb = (EP + 15) / 16;  if (pb > 2048) pb = 2048;
    score_kernel<<<pb, 256, 0, stream>>>(embH, pos_src, pos_dst, EP, -1.0f, acc);
    int ngb = (ENEG + 15) / 16; if (ngb > 4096) ngb = 4096;
    score_kernel<<<ngb, 256, 0, stream>>>(embH, neg_src, neg_dst, ENEG, 1.0f, acc);

    finalize_kernel<<<1, 64, 0, stream>>>(acc, (float*)d_out, EP);
}

// Round 3
// 593.793 us; speedup vs baseline: 1.0778x; 1.0331x over previous
//
#include <hip/hip_runtime.h>
#include <hip/hip_fp16.h>
#include <math.h>

#define D 64

// ---------------- CSR build ----------------

__global__ void hist_kernel(const int* __restrict__ dst, int* __restrict__ deg, int e) {
    int i = blockIdx.x * blockDim.x + threadIdx.x;
    if (i < e) atomicAdd(&deg[dst[i]], 1);
}

__global__ void scan1_kernel(const int* __restrict__ deg, int* __restrict__ rs,
                             int* __restrict__ bsum, int n) {
    __shared__ int s[1024];
    int t = threadIdx.x;
    int i = blockIdx.x * 1024 + t;
    int v = (i < n) ? deg[i] : 0;
    s[t] = v;
    __syncthreads();
    for (int off = 1; off < 1024; off <<= 1) {
        int add = (t >= off) ? s[t - off] : 0;
        __syncthreads();
        s[t] += add;
        __syncthreads();
    }
    if (i < n) rs[i] = s[t] - v;                 // exclusive within block
    if (t == 1023) bsum[blockIdx.x] = s[1023];   // block total
}

__global__ void scan2_kernel(int* __restrict__ bsum, int nb) {
    __shared__ int s[128];
    int t = threadIdx.x;
    int v = (t < nb) ? bsum[t] : 0;
    s[t] = v;
    __syncthreads();
    for (int off = 1; off < 128; off <<= 1) {
        int add = (t >= off) ? s[t - off] : 0;
        __syncthreads();
        s[t] += add;
        __syncthreads();
    }
    if (t < nb) bsum[t] = s[t] - v;              // exclusive block offsets
}

__global__ void scan3_kernel(int* __restrict__ rs, int* __restrict__ cursor,
                             const int* __restrict__ bsum, int n) {
    int i = blockIdx.x * 1024 + threadIdx.x;
    if (i < n) {
        int r = rs[i] + bsum[blockIdx.x];
        rs[i] = r;
        cursor[i] = r;
    }
}

__global__ void scatter_kernel(const int* __restrict__ src, const int* __restrict__ dst,
                               int* __restrict__ cursor, int* __restrict__ csr, int e) {
    int i = blockIdx.x * blockDim.x + threadIdx.x;
    if (i < e) {
        int p = atomicAdd(&cursor[dst[i]], 1);
        csr[p] = src[i];
    }
}

// ---------------- fp32 -> fp16 conversion (features table) ----------------

__global__ __launch_bounds__(256) void f2h_kernel(const float* __restrict__ in,
                                                  __half* __restrict__ out, int n4) {
    int i = blockIdx.x * blockDim.x + threadIdx.x;
    if (i < n4) {
        float4 v = *(const float4*)(in + (size_t)i * 4);
        union { __half2 h[2]; float2 f; } u;
        u.h[0] = __floats2half2_rn(v.x, v.y);
        u.h[1] = __floats2half2_rn(v.z, v.w);
        *(float2*)(out + (size_t)i * 4) = u.f;
    }
}

// ---------------- SAGE layer: aggregate + normalize + GEMM (+ReLU) ----------------
// One 64-lane wave per node. Wave splits into 4 edge-subgroups x 16 lanes;
// each lane loads 8 B (4 halves) of its subgroup's edge row -> 4 rows per
// load instruction, 8 rows in flight with unroll-2. fp16 storage, fp32 math.

__device__ __forceinline__ void unpack4(float2 f, float& x0, float& x1, float& x2, float& x3) {
    __half2 h0 = *reinterpret_cast<__half2*>(&f.x);
    __half2 h1 = *reinterpret_cast<__half2*>(&f.y);
    float2 F0 = __half22float2(h0);
    float2 F1 = __half22float2(h1);
    x0 = F0.x; x1 = F0.y; x2 = F1.x; x3 = F1.y;
}

template<int RELU>
__global__ __launch_bounds__(512) void sage_layer_kernel(
    const __half* __restrict__ in, __half* __restrict__ out,
    const float* __restrict__ W, const float* __restrict__ bias,
    const int* __restrict__ rs, const int* __restrict__ deg,
    const int* __restrict__ csr, int n)
{
    __shared__ float Wl[D * D];
    __shared__ float bl[D];
    for (int i = threadIdx.x; i < D * D; i += blockDim.x) Wl[i] = W[i];
    if (threadIdx.x < D) bl[threadIdx.x] = bias[threadIdx.x];
    __syncthreads();

    const int lane = threadIdx.x & 63;
    const int wid  = threadIdx.x >> 6;
    const int v    = blockIdx.x * (blockDim.x >> 6) + wid;
    if (v >= n) return;

    const int q   = lane & 15;   // which 4-dim chunk this lane owns
    const int grp = lane >> 4;   // edge subgroup 0..3

    const int beg = rs[v];
    const int cnt = deg[v];
    const int end = beg + cnt;

    float a0 = 0.f, a1 = 0.f, a2 = 0.f, a3 = 0.f;

    int eb = beg;
    for (; eb + 8 <= end; eb += 8) {             // 8 edges/iter, 2 loads in flight/lane
        int rA = csr[eb + grp];
        int rB = csr[eb + 4 + grp];
        float2 fA = *(const float2*)(in + (size_t)rA * D + q * 4);
        float2 fB = *(const float2*)(in + (size_t)rB * D + q * 4);
        float x0, x1, x2, x3, y0, y1, y2, y3;
        unpack4(fA, x0, x1, x2, x3);
        unpack4(fB, y0, y1, y2, y3);
        a0 += x0 + y0; a1 += x1 + y1; a2 += x2 + y2; a3 += x3 + y3;
    }
    for (; eb < end; eb += 4) {                  // tail: up to 4 edges/iter, masked
        int e = eb + grp;
        if (e < end) {
            int r = csr[e];
            float2 f = *(const float2*)(in + (size_t)r * D + q * 4);
            float x0, x1, x2, x3;
            unpack4(f, x0, x1, x2, x3);
            a0 += x0; a1 += x1; a2 += x2; a3 += x3;
        }
    }

    // fold the 4 edge subgroups (lanes differing in bits 4,5)
    a0 += __shfl_xor(a0, 16); a0 += __shfl_xor(a0, 32);
    a1 += __shfl_xor(a1, 16); a1 += __shfl_xor(a1, 32);
    a2 += __shfl_xor(a2, 16); a2 += __shfl_xor(a2, 32);
    a3 += __shfl_xor(a3, 16); a3 += __shfl_xor(a3, 32);

    // self term (replicated load across groups) + normalize
    {
        float2 sf = *(const float2*)(in + (size_t)v * D + q * 4);
        float s0, s1, s2, s3;
        unpack4(sf, s0, s1, s2, s3);
        float inv = 1.0f / (float)(cnt + 1);
        a0 = (a0 + s0) * inv; a1 = (a1 + s1) * inv;
        a2 = (a2 + s2) * inv; a3 = (a3 + s3) * inv;
    }

    // row-vector @ W: lane j computes out[j]; a[k] lives in lane (k>>2)&15, elem k&3
    float o = bl[lane];
    #pragma unroll
    for (int kq = 0; kq < 16; ++kq) {
        float v0 = __shfl(a0, kq);
        float v1 = __shfl(a1, kq);
        float v2 = __shfl(a2, kq);
        float v3 = __shfl(a3, kq);
        o = fmaf(v0, Wl[(kq * 4 + 0) * D + lane], o);
        o = fmaf(v1, Wl[(kq * 4 + 1) * D + lane], o);
        o = fmaf(v2, Wl[(kq * 4 + 2) * D + lane], o);
        o = fmaf(v3, Wl[(kq * 4 + 3) * D + lane], o);
    }
    if (RELU) o = fmaxf(o, 0.0f);
    out[(size_t)v * D + lane] = __float2half(o);
}

// ---------------- Scoring: dot + softplus, reduced to a double accumulator ----------------
// 16 lanes per pair; 8 B/lane per row. Unroll 2 pairs for MLP.

__global__ __launch_bounds__(256) void score_kernel(
    const __half* __restrict__ emb,
    const int* __restrict__ a_idx, const int* __restrict__ b_idx,
    int npairs, float sign, double* __restrict__ accum)
{
    const int ll  = threadIdx.x & 15;
    const int gib = threadIdx.x >> 4;
    const int gpb = blockDim.x >> 4;
    int g = blockIdx.x * gpb + gib;
    const int stride = gridDim.x * gpb;

    float local = 0.0f;
    int p = g;
    for (; p + stride < npairs; p += 2 * stride) {
        int p2 = p + stride;
        int ai = a_idx[p],  bi = b_idx[p];
        int ci = a_idx[p2], di = b_idx[p2];
        float2 fa = *(const float2*)(emb + (size_t)ai * D + ll * 4);
        float2 fb = *(const float2*)(emb + (size_t)bi * D + ll * 4);
        float2 fc = *(const float2*)(emb + (size_t)ci * D + ll * 4);
        float2 fd = *(const float2*)(emb + (size_t)di * D + ll * 4);
        float A0,A1,A2,A3,B0,B1,B2,B3,C0,C1,C2,C3,E0,E1,E2,E3;
        unpack4(fa, A0,A1,A2,A3);
        unpack4(fb, B0,B1,B2,B3);
        unpack4(fc, C0,C1,C2,C3);
        unpack4(fd, E0,E1,E2,E3);
        float d0 = A0*B0 + A1*B1 + A2*B2 + A3*B3;
        float d1 = C0*E0 + C1*E1 + C2*E2 + C3*E3;
        d0 += __shfl_xor(d0, 1); d1 += __shfl_xor(d1, 1);
        d0 += __shfl_xor(d0, 2); d1 += __shfl_xor(d1, 2);
        d0 += __shfl_xor(d0, 4); d1 += __shfl_xor(d1, 4);
        d0 += __shfl_xor(d0, 8); d1 += __shfl_xor(d1, 8);
        if (ll == 0) {
            float x0 = sign * d0, x1 = sign * d1;
            local += fmaxf(x0, 0.0f) + log1pf(expf(-fabsf(x0)));
            local += fmaxf(x1, 0.0f) + log1pf(expf(-fabsf(x1)));
        }
    }
    for (; p < npairs; p += stride) {
        int ai = a_idx[p], bi = b_idx[p];
        float2 fa = *(const float2*)(emb + (size_t)ai * D + ll * 4);
        float2 fb = *(const float2*)(emb + (size_t)bi * D + ll * 4);
        float A0,A1,A2,A3,B0,B1,B2,B3;
        unpack4(fa, A0,A1,A2,A3);
        unpack4(fb, B0,B1,B2,B3);
        float d = A0*B0 + A1*B1 + A2*B2 + A3*B3;
        d += __shfl_xor(d, 1);
        d += __shfl_xor(d, 2);
        d += __shfl_xor(d, 4);
        d += __shfl_xor(d, 8);
        if (ll == 0) {
            float x = sign * d;
            local += fmaxf(x, 0.0f) + log1pf(expf(-fabsf(x)));
        }
    }

    __shared__ float red[256];
    red[threadIdx.x] = local;
    __syncthreads();
    for (int s = blockDim.x / 2; s > 0; s >>= 1) {
        if ((int)threadIdx.x < s) red[threadIdx.x] += red[threadIdx.x + s];
        __syncthreads();
    }
    if (threadIdx.x == 0) atomicAdd(accum, (double)red[0]);
}

__global__ void finalize_kernel(const double* __restrict__ acc, float* __restrict__ out, int ep) {
    if (threadIdx.x == 0 && blockIdx.x == 0)
        out[0] = (float)(acc[0] / (double)ep);
}

// ---------------- launch ----------------

extern "C" void kernel_launch(void* const* d_in, const int* in_sizes, int n_in,
                              void* d_out, int out_size, void* d_ws, size_t ws_size,
                              hipStream_t stream) {
    const float* features = (const float*)d_in[0];
    const float* W1 = (const float*)d_in[1];
    const float* b1 = (const float*)d_in[2];
    const float* W2 = (const float*)d_in[3];
    const float* b2 = (const float*)d_in[4];
    const int* src     = (const int*)d_in[5];
    const int* dst     = (const int*)d_in[6];
    const int* pos_src = (const int*)d_in[7];
    const int* pos_dst = (const int*)d_in[8];
    const int* neg_src = (const int*)d_in[9];
    const int* neg_dst = (const int*)d_in[10];

    const int N    = in_sizes[0] / D;
    const int E    = in_sizes[5];
    const int EP   = in_sizes[7];
    const int ENEG = in_sizes[9];

    char* ws = (char*)d_ws;
    size_t off = 0;
    auto alloc = [&](size_t bytes) -> void* {
        void* p = ws + off;
        off += (bytes + 255) & ~(size_t)255;
        return p;
    };
    int*    deg    = (int*)   alloc((size_t)N * 4);
    int*    rs     = (int*)   alloc((size_t)(N + 1) * 4);
    int*    cursor = (int*)   alloc((size_t)N * 4);
    int*    bsum   = (int*)   alloc(1024 * 4);
    int*    csr    = (int*)   alloc((size_t)E * 4);
    __half* featH  = (__half*)alloc((size_t)N * D * 2);
    __half* hH     = (__half*)alloc((size_t)N * D * 2);
    __half* embH   = (__half*)alloc((size_t)N * D * 2);
    double* acc    = (double*)alloc(8);

    hipMemsetAsync(deg, 0, (size_t)N * 4, stream);
    hipMemsetAsync(acc, 0, 8, stream);

    const int eb  = (E + 255) / 256;
    const int nb1 = (N + 1023) / 1024;   // 98 for N=100000, fits scan2's 128 threads

    hist_kernel<<<eb, 256, 0, stream>>>(dst, deg, E);
    scan1_kernel<<<nb1, 1024, 0, stream>>>(deg, rs, bsum, N);
    scan2_kernel<<<1, 128, 0, stream>>>(bsum, nb1);
    scan3_kernel<<<nb1, 1024, 0, stream>>>(rs, cursor, bsum, N);
    scatter_kernel<<<eb, 256, 0, stream>>>(src, dst, cursor, csr, E);

    const int n4 = (N * D) / 4;
    f2h_kernel<<<(n4 + 255) / 256, 256, 0, stream>>>(features, featH, n4);

    const int lb = (N + 7) / 8;          // 8 waves (nodes) per 512-thread block
    sage_layer_kernel<1><<<lb, 512, 0, stream>>>(featH, hH, W1, b1, rs, deg, csr, N);
    sage_layer_kernel<0><<<lb, 512, 0, stream>>>(hH, embH, W2, b2, rs, deg, csr, N);

    int pb = (EP + 15) / 16;  if (pb > 2048) pb = 2048;
    score_kernel<<<pb, 256, 0, stream>>>(embH, pos_src, pos_dst, EP, -1.0f, acc);
    int ngb = (ENEG + 15) / 16; if (ngb > 4096) ngb = 4096;
    score_kernel<<<ngb, 256, 0, stream>>>(embH, neg_src, neg_dst, ENEG, 1.0f, acc);

    finalize_kernel<<<1, 64, 0, stream>>>(acc, (float*)d_out, EP);
}